// Round 1
// baseline (382.194 us; speedup 1.0000x reference)
//
#include <hip/hip_runtime.h>
#include <hip/hip_bf16.h>
#include <math.h>

#define N_NODES    100000
#define N_EDGES    1600000
#define NUM_GRAPHS 512
#define D2 50
#define D3 15
#define D5 10
#define NCLS 6
#define BN_EPS 1e-5f

// global bf16 weight buffer layout (elements), padded/transposed
// ew1T [64 m][40 k] : k0-2 x_row, k3 bias, k4-6 x_col, k8-10 ea
// ew2T [16 m][72 k] : k0-49 h1, k50 bias
// nw1T [64 m][40 k] : k0-14 e2, k16-18 x_col, k19 bias
// nw2T [16 m][72 k] : k0-49 h2, k50 bias
#define W_EW1T 0
#define W_EW2T 2560
#define W_NW1T 3712
#define W_NW2T 6272
#define W_TOTAL 7680

#define EDGE_BLOCKS 1024                 // 4 blocks/CU exactly (LDS-limited)
#define EDGE_WAVES  (EDGE_BLOCKS * 4)    // 4096
#define TILES32     (N_EDGES / 32)       // 50000; grid-stride over tiles

#define GPAD 17                          // LDS graph-record stride (odd -> all 32 banks)

typedef __attribute__((ext_vector_type(8))) short short8;
typedef __attribute__((ext_vector_type(4))) float float4_;
union BU { unsigned u[4]; short8 s; };

__device__ __forceinline__ unsigned short f2bf(float f) {
    __hip_bfloat16 h = __float2bfloat16(f);
    union { __hip_bfloat16 h; unsigned short u; } c; c.h = h; return c.u;
}
// gfx950 native packed f32->bf16 (RNE)
__device__ __forceinline__ unsigned pkbf(float a, float b) {
    unsigned r;
    asm("v_cvt_pk_bf16_f32 %0, %1, %2" : "=v"(r) : "v"(a), "v"(b));
    return r;
}
__device__ __forceinline__ unsigned bp(int s4, unsigned v) {
    return (unsigned)__builtin_amdgcn_ds_bpermute(s4, (int)v);
}

// ---------- fused prep: weight transpose (single bf16) + x pad + histograms ----------
// NOTE: degree histogram must stay SCALAR — int4 version failed correctness in
// R12/R13 (intermittent post-timing divergence); scalar passed R10/R11.
__global__ __launch_bounds__(256) void prep_kernel(
    const float* __restrict__ ew1, const float* __restrict__ eb1,
    const float* __restrict__ ew2, const float* __restrict__ eb2,
    const float* __restrict__ nw1, const float* __restrict__ nb1,
    const float* __restrict__ nw2, const float* __restrict__ nb2,
    unsigned short* __restrict__ wh,
    const float* __restrict__ x, ushort4* __restrict__ x4b,
    const int* __restrict__ edge_index, int* __restrict__ counts,
    const int* __restrict__ batch, float* __restrict__ gsum)
{
    __shared__ int bh[NUM_GRAPHS];       // per-block node-count histogram
    int gtid = blockIdx.x * 256 + threadIdx.x;
    int gsz = gridDim.x * 256;

    for (int i = threadIdx.x; i < NUM_GRAPHS; i += 256) bh[i] = 0;
    __syncthreads();

    for (int i = gtid; i < W_TOTAL; i += gsz) {
        float v = 0.0f;
        if (i < W_EW2T) {
            int m = i / 40, k = i % 40;
            if (m < 50) {
                if (k < 3)                 v = ew1[k * 50 + m];
                else if (k == 3)           v = eb1[m];
                else if (k >= 4 && k < 7)  v = ew1[(k - 1) * 50 + m];
                else if (k >= 8 && k < 11) v = ew1[(k - 2) * 50 + m];
            }
        } else if (i < W_NW1T) {
            int j = i - W_EW2T; int m = j / 72, k = j % 72;
            if (m < 15) { if (k < 50) v = ew2[k * 15 + m]; else if (k == 50) v = eb2[m]; }
        } else if (i < W_NW2T) {
            int j = i - W_NW1T; int m = j / 40, k = j % 40;
            if (m < 50) {
                if (k < 15)                  v = nw1[(3 + k) * 50 + m];
                else if (k >= 16 && k < 19)  v = nw1[(k - 16) * 50 + m];
                else if (k == 19)            v = nb1[m];
            }
        } else if (i < 7424) {
            int j = i - W_NW2T; int m = j / 72, k = j % 72;
            if (m < 15) { if (k < 50) v = nw2[k * 15 + m]; else if (k == 50) v = nb2[m]; }
        }
        wh[i] = f2bf(v);
    }

    for (int n = gtid; n < N_NODES; n += gsz) {
        ushort4 v;
        v.x = f2bf(x[n * 3 + 0]); v.y = f2bf(x[n * 3 + 1]);
        v.z = f2bf(x[n * 3 + 2]); v.w = 0;
        x4b[n] = v;
        atomicAdd(&bh[batch[n]], 1);     // node count per graph (batch sorted -> few addrs)
    }

    for (int e = gtid; e < N_EDGES; e += gsz)
        atomicAdd(&counts[edge_index[e]], 1);

    __syncthreads();
    for (int i = threadIdx.x; i < NUM_GRAPHS; i += 256) {
        int v = bh[i];
        if (v) atomicAdd(&gsum[i * 16 + 15], (float)v);
    }
}

// ---------- per-edge input fetch: each (quad,n) lane owns edge n's slice ----------
struct EIn { unsigned w0, w1, w2, w3, h0, h1; int g; float invd; };

__device__ __forceinline__ EIn load_in(int ebase, int n, int quad,
    const int* __restrict__ edge_index, const ushort4* __restrict__ x4b,
    const float* __restrict__ edge_attr,
    const int* __restrict__ counts, const int* __restrict__ batch)
{
    EIn r; r.w0 = r.w1 = r.w2 = r.w3 = 0; r.h0 = r.h1 = 0; r.g = 0; r.invd = 0.0f;
    int e = ebase + n;
    if (quad == 0) {
        int row = edge_index[e];
        int col = edge_index[N_EDGES + e];
        ushort4 xr = x4b[row];
        ushort4 xc = x4b[col];
        r.w0 = (unsigned)xr.x | ((unsigned)xr.y << 16);   // k0,k1 = x_row
        r.w1 = (unsigned)xr.z | (0x3F80u << 16);          // k2, k3=bias
        r.w2 = (unsigned)xc.x | ((unsigned)xc.y << 16);   // k4,k5 = x_col
        r.w3 = (unsigned)xc.z;                            // k6, k7=0
        r.g = batch[row];                                 // target graph
        r.invd = 1.0f / (float)counts[row];               // deg >= 1 (this edge exists)
    } else if (quad == 1) {
        r.w0 = pkbf(edge_attr[e * 3 + 0], edge_attr[e * 3 + 1]);  // k8,k9
        r.w1 = pkbf(edge_attr[e * 3 + 2], 0.0f);                  // k10, k11=0
    } else if (quad == 2) {
        int col = edge_index[N_EDGES + e];
        ushort4 xc = x4b[col];
        r.h0 = (unsigned)xc.x | ((unsigned)xc.y << 16);   // nodeMLP k16,k17
        r.h1 = (unsigned)xc.z | (0x3F80u << 16);          // k18, k19=bias
    }
    return r;
}

// 64-ch C output (4 blocks, packed pairs U[4][2]) -> two K=32 B fragments
__device__ __forceinline__ void perm64(const unsigned U[4][2], int s0, int s1, bool hi,
                                       short8& Bc0, short8& Bc1)
{
    BU b0, b1;
    {
        unsigned a0 = bp(s0, U[0][0]), a1 = bp(s0, U[1][0]);
        unsigned a2 = bp(s0, U[0][1]), a3 = bp(s0, U[1][1]);
        unsigned a4 = bp(s1, U[0][0]), a5 = bp(s1, U[1][0]);
        unsigned a6 = bp(s1, U[0][1]), a7 = bp(s1, U[1][1]);
        b0.u[0] = hi ? a1 : a0;
        b0.u[1] = hi ? a3 : a2;
        b0.u[2] = hi ? a5 : a4;
        b0.u[3] = hi ? a7 : a6;
    }
    {
        unsigned a0 = bp(s0, U[2][0]), a1 = bp(s0, U[3][0]);
        unsigned a2 = bp(s0, U[2][1]), a3 = bp(s0, U[3][1]);
        unsigned a4 = bp(s1, U[2][0]), a5 = bp(s1, U[3][0]);
        unsigned a6 = bp(s1, U[2][1]), a7 = bp(s1, U[3][1]);
        b1.u[0] = hi ? a1 : a0;
        b1.u[1] = hi ? a3 : a2;
        b1.u[2] = hi ? a5 : a4;
        b1.u[3] = hi ? a7 : a6;
    }
    Bc0 = b0.s; Bc1 = b1.s;
}

// 16-ch C output (packed U2[2]) + static x_col/bias part -> K=32 B fragment
__device__ __forceinline__ short8 perm16(const unsigned U2[2], int s0, int s1,
                                         int quad, unsigned h0, unsigned h1)
{
    BU d;
    d.u[0] = bp(s0, U2[0]);
    d.u[1] = bp(s0, U2[1]);
    d.u[2] = bp(s1, U2[0]);
    d.u[3] = bp(s1, U2[1]);
    if (quad == 2) { d.u[0] = h0; d.u[1] = h1; d.u[2] = 0; d.u[3] = 0; }
    else if (quad == 3) { d.u[0] = 0; d.u[1] = 0; d.u[2] = 0; d.u[3] = 0; }
    return d.s;
}

// ---------- MFMA edge MLP fused with per-graph accumulation ----------
// msg never materialized: u[g] = (1/cnt_g) * sum_e msg_e / deg(row_e)
// NOTE: no min-waves __launch_bounds__ — (256,4) miscompiled (R12).
__global__ __launch_bounds__(256) void edge_fused_kernel(
    const unsigned short* __restrict__ wh_g,
    const ushort4* __restrict__ x4b, const float* __restrict__ edge_attr,
    const int* __restrict__ edge_index,
    const int* __restrict__ counts, const int* __restrict__ batch,
    float* __restrict__ partial)
{
    __shared__ float acc[NUM_GRAPHS * GPAD];   // 34816 B; stride 17 -> conflict-spread
    int tid = threadIdx.x, wave = tid >> 6, lane = tid & 63;
    int n = lane & 15, quad = lane >> 4;

    for (int i = tid; i < NUM_GRAPHS * GPAD; i += 256) acc[i] = 0.0f;
    __syncthreads();

    // A-fragments (weights) -> registers, once per wave
    short8 A1[4], A3[4];
    #pragma unroll
    for (int t4 = 0; t4 < 4; t4++) {
        A1[t4] = *(const short8*)(wh_g + W_EW1T + (t4 * 16 + n) * 40 + quad * 8);
        A3[t4] = *(const short8*)(wh_g + W_NW1T + (t4 * 16 + n) * 40 + quad * 8);
    }
    short8 A2[2], A4[2];
    #pragma unroll
    for (int kc = 0; kc < 2; kc++) {
        A2[kc] = *(const short8*)(wh_g + W_EW2T + n * 72 + kc * 32 + quad * 8);
        A4[kc] = *(const short8*)(wh_g + W_NW2T + n * 72 + kc * 32 + quad * 8);
    }

    int s0 = ((quad & 1) * 32 + n) * 4;   // byte index for bpermute (lane*4)
    int s1 = s0 + 64;
    bool hi = (quad & 2) != 0;

    const float4_ Z0 = {0.f, 0.f, 0.f, 0.f};   // one zeroed acc quad, reused

    int t = blockIdx.x * 4 + wave;        // first tile for this wave (< TILES32 always)
    EIn cur0 = load_in(t * 32,      n, quad, edge_index, x4b, edge_attr, counts, batch);
    EIn cur1 = load_in(t * 32 + 16, n, quad, edge_index, x4b, edge_attr, counts, batch);

    for (;;) {
        int g0 = __shfl(cur0.g, n);
        float q0 = __shfl(cur0.invd, n);
        int g1 = __shfl(cur1.g, n);
        float q1 = __shfl(cur1.invd, n);

        int tn = t + EDGE_WAVES;
        bool more = (tn < TILES32);
        EIn nx0, nx1;
        nx0.w0 = nx0.w1 = nx0.w2 = nx0.w3 = nx0.h0 = nx0.h1 = 0; nx0.g = 0; nx0.invd = 0.f;
        nx1 = nx0;
        if (more) {
            nx0 = load_in(tn * 32,      n, quad, edge_index, x4b, edge_attr, counts, batch);
            nx1 = load_in(tn * 32 + 16, n, quad, edge_index, x4b, edge_attr, counts, batch);
        }

        // B1 direct from registers
        BU t0, t1;
        t0.u[0] = cur0.w0; t0.u[1] = cur0.w1; t0.u[2] = cur0.w2; t0.u[3] = cur0.w3;
        t1.u[0] = cur1.w0; t1.u[1] = cur1.w1; t1.u[2] = cur1.w2; t1.u[3] = cur1.w3;
        short8 B1a = t0.s, B1b = t1.s;

        // ---- layer 1: [64ch] x K=32 ----
        unsigned U1a[4][2], U1b[4][2];
        #pragma unroll
        for (int t4 = 0; t4 < 4; t4++) {
            float4_ za = __builtin_amdgcn_mfma_f32_16x16x32_bf16(A1[t4], B1a, Z0, 0, 0, 0);
            float4_ zb = __builtin_amdgcn_mfma_f32_16x16x32_bf16(A1[t4], B1b, Z0, 0, 0, 0);
            U1a[t4][0] = pkbf(fmaxf(za[0], 0.f), fmaxf(za[1], 0.f));
            U1a[t4][1] = pkbf(fmaxf(za[2], 0.f), fmaxf(za[3], 0.f));
            U1b[t4][0] = pkbf(fmaxf(zb[0], 0.f), fmaxf(zb[1], 0.f));
            U1b[t4][1] = pkbf(fmaxf(zb[2], 0.f), fmaxf(zb[3], 0.f));
        }

        short8 B2a0, B2a1, B2b0, B2b1;
        perm64(U1a, s0, s1, hi, B2a0, B2a1);
        perm64(U1b, s0, s1, hi, B2b0, B2b1);
        // bias=1 at k=50: kc=1, quad_b=2, j=2 -> low half of uint[1]
        if (quad == 2) {
            BU fa, fb; fa.s = B2a1; fb.s = B2b1;
            fa.u[1] = (fa.u[1] & 0xFFFF0000u) | 0x3F80u;
            fb.u[1] = (fb.u[1] & 0xFFFF0000u) | 0x3F80u;
            B2a1 = fa.s; B2b1 = fb.s;
        }

        // ---- layer 2: [16ch] x K=64 ----
        float4_ a2a = __builtin_amdgcn_mfma_f32_16x16x32_bf16(A2[0], B2a0, Z0, 0, 0, 0);
        float4_ a2b = __builtin_amdgcn_mfma_f32_16x16x32_bf16(A2[0], B2b0, Z0, 0, 0, 0);
        a2a = __builtin_amdgcn_mfma_f32_16x16x32_bf16(A2[1], B2a1, a2a, 0, 0, 0);
        a2b = __builtin_amdgcn_mfma_f32_16x16x32_bf16(A2[1], B2b1, a2b, 0, 0, 0);

        unsigned U2a[2] = { pkbf(a2a[0], a2a[1]), pkbf(a2a[2], a2a[3]) };
        unsigned U2b[2] = { pkbf(a2b[0], a2b[1]), pkbf(a2b[2], a2b[3]) };

        short8 B3a = perm16(U2a, s0, s1, quad, cur0.h0, cur0.h1);
        short8 B3b = perm16(U2b, s0, s1, quad, cur1.h0, cur1.h1);

        // ---- layer 3: [64ch] x K=32 ----
        unsigned U3a[4][2], U3b[4][2];
        #pragma unroll
        for (int t4 = 0; t4 < 4; t4++) {
            float4_ za = __builtin_amdgcn_mfma_f32_16x16x32_bf16(A3[t4], B3a, Z0, 0, 0, 0);
            float4_ zb = __builtin_amdgcn_mfma_f32_16x16x32_bf16(A3[t4], B3b, Z0, 0, 0, 0);
            U3a[t4][0] = pkbf(fmaxf(za[0], 0.f), fmaxf(za[1], 0.f));
            U3a[t4][1] = pkbf(fmaxf(za[2], 0.f), fmaxf(za[3], 0.f));
            U3b[t4][0] = pkbf(fmaxf(zb[0], 0.f), fmaxf(zb[1], 0.f));
            U3b[t4][1] = pkbf(fmaxf(zb[2], 0.f), fmaxf(zb[3], 0.f));
        }

        short8 B4a0, B4a1, B4b0, B4b1;
        perm64(U3a, s0, s1, hi, B4a0, B4a1);
        perm64(U3b, s0, s1, hi, B4b0, B4b1);
        if (quad == 2) {
            BU fa, fb; fa.s = B4a1; fb.s = B4b1;
            fa.u[1] = (fa.u[1] & 0xFFFF0000u) | 0x3F80u;
            fb.u[1] = (fb.u[1] & 0xFFFF0000u) | 0x3F80u;
            B4a1 = fa.s; B4b1 = fb.s;
        }

        // ---- layer 4: [16ch] x K=64 ----
        float4_ ma = __builtin_amdgcn_mfma_f32_16x16x32_bf16(A4[0], B4a0, Z0, 0, 0, 0);
        float4_ mb = __builtin_amdgcn_mfma_f32_16x16x32_bf16(A4[0], B4b0, Z0, 0, 0, 0);
        ma = __builtin_amdgcn_mfma_f32_16x16x32_bf16(A4[1], B4a1, ma, 0, 0, 0);
        mb = __builtin_amdgcn_mfma_f32_16x16x32_bf16(A4[1], B4b1, mb, 0, 0, 0);

        // ---- per-graph accumulate: msg * invd into LDS (fire-and-forget) ----
        // lane (quad,n) holds channels quad*4..quad*4+3 of edge n (row = quad*4+reg)
        float* a0 = &acc[g0 * GPAD + quad * 4];
        float* a1 = &acc[g1 * GPAD + quad * 4];
        atomicAdd(&a0[0], ma[0] * q0);
        atomicAdd(&a0[1], ma[1] * q0);
        atomicAdd(&a0[2], ma[2] * q0);
        atomicAdd(&a1[0], mb[0] * q1);
        atomicAdd(&a1[1], mb[1] * q1);
        atomicAdd(&a1[2], mb[2] * q1);
        if (quad != 3) {                    // channel 15 is structurally zero
            atomicAdd(&a0[3], ma[3] * q0);
            atomicAdd(&a1[3], mb[3] * q1);
        }

        if (!more) break;
        cur0 = nx0; cur1 = nx1; t = tn;
    }

    // ---- flush block accumulator to partial[block][512][16] (coalesced) ----
    __syncthreads();
    float* pb = partial + (size_t)blockIdx.x * (NUM_GRAPHS * 16);
    for (int i = tid; i < NUM_GRAPHS * 16; i += 256)
        pb[i] = acc[(i >> 4) * GPAD + (i & 15)];
}

// ---------- reduce partials: one block per graph ----------
__global__ __launch_bounds__(256) void reduce_kernel(
    const float* __restrict__ partial, float* __restrict__ gsum)
{
    __shared__ float red[256];
    int g = blockIdx.x;
    float s = 0.0f;
    for (int j = threadIdx.x; j < EDGE_BLOCKS * 16; j += 256) {
        int b = j >> 4, c = j & 15;
        s += partial[(size_t)b * (NUM_GRAPHS * 16) + g * 16 + c];
    }
    red[threadIdx.x] = s;        // channel = threadIdx.x & 15 (invariant mod 16)
    __syncthreads();
    if (threadIdx.x < 16) {
        float t = 0.0f;
        #pragma unroll
        for (int k = 0; k < 16; k++) t += red[k * 16 + threadIdx.x];
        // ch15 partials are exactly 0; gsum ch15 holds node count from prep
        gsum[g * 16 + threadIdx.x] += t;
    }
}

// ---------- head ----------
__global__ __launch_bounds__(512) void head_kernel(
    const float* __restrict__ gsum,
    const float* __restrict__ fc1w, const float* __restrict__ fc1b,
    const float* __restrict__ gamma, const float* __restrict__ beta,
    const float* __restrict__ fc2w, const float* __restrict__ fc2b,
    float* __restrict__ out)
{
    __shared__ float ssum[D5], ssq[D5], smu[D5], sistd[D5];
    int g = threadIdx.x;
    if (g < D5) { ssum[g] = 0.0f; ssq[g] = 0.0f; }
    __syncthreads();

    const float* src = gsum + (size_t)g * 16;
    float inv = 1.0f / fmaxf(src[15], 1.0f);
    float u[D3];
    #pragma unroll
    for (int k = 0; k < D3; k++) u[k] = src[k] * inv;

    float h[D5];
    #pragma unroll
    for (int c = 0; c < D5; c++) h[c] = fc1b[c];
    #pragma unroll
    for (int k = 0; k < D3; k++) {
        float v = u[k];
        #pragma unroll
        for (int c = 0; c < D5; c++) h[c] = fmaf(v, fc1w[k * D5 + c], h[c]);
    }

    int lane = threadIdx.x & 63;
    #pragma unroll
    for (int c = 0; c < D5; c++) {
        float v = h[c];
        float v2 = v * v;
        #pragma unroll
        for (int off = 32; off >= 1; off >>= 1) {
            v  += __shfl_xor(v,  off);
            v2 += __shfl_xor(v2, off);
        }
        if (lane == 0) { atomicAdd(&ssum[c], v); atomicAdd(&ssq[c], v2); }
    }
    __syncthreads();
    if (g < D5) {
        float mu = ssum[g] * (1.0f / NUM_GRAPHS);
        float var = ssq[g] * (1.0f / NUM_GRAPHS) - mu * mu;
        smu[g] = mu;
        sistd[g] = rsqrtf(var + BN_EPS);
    }
    __syncthreads();

    float hn[D5];
    #pragma unroll
    for (int c = 0; c < D5; c++) {
        float v = gamma[c] * (h[c] - smu[c]) * sistd[c] + beta[c];
        hn[c] = fmaxf(v, 0.0f);
    }

    float lg[NCLS];
    #pragma unroll
    for (int j = 0; j < NCLS; j++) lg[j] = fc2b[j];
    #pragma unroll
    for (int c = 0; c < D5; c++) {
        float v = hn[c];
        #pragma unroll
        for (int j = 0; j < NCLS; j++) lg[j] = fmaf(v, fc2w[c * NCLS + j], lg[j]);
    }

    float m = lg[0];
    #pragma unroll
    for (int j = 1; j < NCLS; j++) m = fmaxf(m, lg[j]);
    float se = 0.0f;
    #pragma unroll
    for (int j = 0; j < NCLS; j++) se += expf(lg[j] - m);
    float lse = logf(se);
    #pragma unroll
    for (int j = 0; j < NCLS; j++) out[g * NCLS + j] = lg[j] - m - lse;
}

extern "C" void kernel_launch(void* const* d_in, const int* in_sizes, int n_in,
                              void* d_out, int out_size, void* d_ws, size_t ws_size,
                              hipStream_t stream) {
    const float* x         = (const float*)d_in[0];
    const float* edge_attr = (const float*)d_in[1];
    const float* ew1  = (const float*)d_in[2];
    const float* eb1  = (const float*)d_in[3];
    const float* ew2  = (const float*)d_in[4];
    const float* eb2  = (const float*)d_in[5];
    const float* nw1  = (const float*)d_in[6];
    const float* nb1  = (const float*)d_in[7];
    const float* nw2  = (const float*)d_in[8];
    const float* nb2  = (const float*)d_in[9];
    const float* fc1w = (const float*)d_in[10];
    const float* fc1b = (const float*)d_in[11];
    const float* gamma= (const float*)d_in[12];
    const float* beta = (const float*)d_in[13];
    const float* fc2w = (const float*)d_in[14];
    const float* fc2b = (const float*)d_in[15];
    const int* edge_index = (const int*)d_in[16];
    const int* batch      = (const int*)d_in[17];

    // workspace layout (16B-aligned slices)
    char* p = (char*)d_ws;
    float* partial = (float*)p;        p += (size_t)EDGE_BLOCKS * NUM_GRAPHS * 16 * sizeof(float); // 33.5 MB
    int* counts  = (int*)p;            p += (size_t)N_NODES * sizeof(int);
    ushort4* x4b = (ushort4*)p;        p += (size_t)N_NODES * sizeof(ushort4);     // 0.8 MB
    float* gsum  = (float*)p;          p += (size_t)NUM_GRAPHS * 16 * sizeof(float);
    unsigned short* wh = (unsigned short*)p; p += W_TOTAL * sizeof(unsigned short);

    hipMemsetAsync(counts, 0, (size_t)N_NODES * sizeof(int), stream);
    hipMemsetAsync(gsum, 0, (size_t)NUM_GRAPHS * 16 * sizeof(float), stream);

    int egrid = (N_EDGES + 255) / 256;

    prep_kernel<<<egrid, 256, 0, stream>>>(
        ew1, eb1, ew2, eb2, nw1, nb1, nw2, nb2, wh,
        x, x4b, edge_index, counts, batch, gsum);
    edge_fused_kernel<<<EDGE_BLOCKS, 256, 0, stream>>>(
        wh, x4b, edge_attr, edge_index, counts, batch, partial);
    reduce_kernel<<<NUM_GRAPHS, 256, 0, stream>>>(partial, gsum);
    head_kernel<<<1, 512, 0, stream>>>(
        gsum, fc1w, fc1b, gamma, beta, fc2w, fc2b, (float*)d_out);
}